// Round 4
// baseline (300.932 us; speedup 1.0000x reference)
//
// v3 resubmit — identical algorithm; rounds 1-3 failed in infrastructure
#include <hip/hip_runtime.h>
#include <hip/hip_bf16.h>
#include <math.h>

#define NN 8
#define CC 256
#define LL 8192
#define KK 3
#define GG 8
#define GCC 32
#define OMD 48  // 2*G*K
#define TILE_L 128

__device__ inline ushort f2bf(float f) {
    uint u = __float_as_uint(f);
    u += 0x7fffu + ((u >> 16) & 1u);   // RNE
    return (ushort)(u >> 16);
}

// ---------------- kernel 0: transpose om_w [48][256] -> wT [256][48] ----------
__global__ void k_transpose_w(const float* __restrict__ w, float* __restrict__ wT) {
    int idx = blockIdx.x * 256 + threadIdx.x;
    if (idx < OMD * CC) {
        int o = idx / CC, c = idx % CC;
        wT[c * OMD + o] = w[idx];
    }
}

// ---------------- kernel 1: LN + GELU + om projection -------------------------
// one thread per (n,l) position. x is [N,C,L] (stride-L channel reads, coalesced
// across lanes since consecutive threads = consecutive l).
__global__ __launch_bounds__(256) void k_ln_gelu_om(
    const float* __restrict__ x,
    const float* __restrict__ ln_w, const float* __restrict__ ln_b,
    const float* __restrict__ wT,  const float* __restrict__ om_b,
    __hip_bfloat16* __restrict__ xa, float* __restrict__ om)
{
    int pos = blockIdx.x * 256 + threadIdx.x;   // N*L = 65536 total
    int n = pos >> 13;
    int l = pos & (LL - 1);
    const float* xp = x + (size_t)n * CC * LL + l;

    // pass 1: mean/var
    float sum = 0.f, sq = 0.f;
    #pragma unroll 16
    for (int c = 0; c < CC; ++c) {
        float v = xp[(size_t)c * LL];
        sum += v; sq += v * v;
    }
    float mean = sum * (1.f / 256.f);
    float var  = sq * (1.f / 256.f) - mean * mean;
    float rstd = rsqrtf(var + 1e-6f);

    // om accumulators
    float acc[OMD];
    #pragma unroll
    for (int o = 0; o < OMD; ++o) acc[o] = om_b[o];

    __hip_bfloat16* xap = xa + (size_t)pos * CC;

    // pass 2: normalize, gelu, store bf16, accumulate projection
    for (int c0 = 0; c0 < CC; c0 += 8) {
        ushort pk[8];
        #pragma unroll
        for (int j = 0; j < 8; ++j) {
            int c = c0 + j;
            float v  = xp[(size_t)c * LL];
            float xn = (v - mean) * rstd * ln_w[c] + ln_b[c];
            float g  = xn * 0.5f * (1.f + erff(xn * 0.70710678118654752440f));
            pk[j] = f2bf(g);
            const float* wrow = wT + c * OMD;
            #pragma unroll
            for (int o = 0; o < OMD; ++o) acc[o] = fmaf(wrow[o], g, acc[o]);
        }
        uint4 vv;
        vv.x = (uint)pk[0] | ((uint)pk[1] << 16);
        vv.y = (uint)pk[2] | ((uint)pk[3] << 16);
        vv.z = (uint)pk[4] | ((uint)pk[5] << 16);
        vv.w = (uint)pk[6] | ((uint)pk[7] << 16);
        *reinterpret_cast<uint4*>(reinterpret_cast<char*>(xap) + c0 * 2) = vv;
    }

    float* omp = om + (size_t)pos * OMD;
    #pragma unroll
    for (int o = 0; o < OMD; o += 4) {
        float4 v4 = make_float4(acc[o], acc[o+1], acc[o+2], acc[o+3]);
        *reinterpret_cast<float4*>(omp + o) = v4;
    }
}

// ---------------- kernel 2: deformable gather + mask aggregation --------------
// grid (L/TILE_L, G, N), block 256. xa is bf16 [N,L,C].
__global__ __launch_bounds__(256) void k_dcn(
    const __hip_bfloat16* __restrict__ xa, const float* __restrict__ om,
    float* __restrict__ out)
{
    int lt = blockIdx.x, g = blockIdx.y, n = blockIdx.z;
    int l0 = lt * TILE_L;

    __shared__ int   i0_s[TILE_L * KK];
    __shared__ int   i1_s[TILE_L * KK];
    __shared__ float w0_s[TILE_L * KK];
    __shared__ float w1_s[TILE_L * KK];
    __shared__ float out_s[GCC][TILE_L + 1];

    int t = threadIdx.x;

    // precompute interp data per (l,k), mask folded into weights
    for (int idx = t; idx < TILE_L * KK; idx += 256) {
        int ll = idx / KK, k = idx - KK * (idx / KK);
        int l = l0 + ll;
        const float* omp = om + ((size_t)n * LL + l) * OMD;
        float off  = omp[g * KK + k];
        float mask = omp[GG * KK + g * KK + k];
        float p  = (float)(l - 1 + k) + off;
        float p0 = floorf(p);
        float w1 = p - p0;
        float w0 = 1.f - w1;
        int i0 = (int)p0;
        int i1 = i0 + 1;
        float ws0 = (i0 >= 0 && i0 < LL) ? mask * w0 : 0.f;
        float ws1 = (i1 >= 0 && i1 < LL) ? mask * w1 : 0.f;
        i0_s[idx] = min(max(i0, 0), LL - 1);
        i1_s[idx] = min(max(i1, 0), LL - 1);
        w0_s[idx] = ws0;
        w1_s[idx] = ws1;
    }
    __syncthreads();

    int c  = t & 31;       // channel within group
    int lq = t >> 5;       // 0..7
    const __hip_bfloat16* xab = xa + (size_t)n * LL * CC + g * GCC + c;

    for (int it = 0; it < TILE_L / 8; ++it) {
        int ll = it * 8 + lq;
        float acc = 0.f;
        #pragma unroll
        for (int k = 0; k < KK; ++k) {
            int idx = ll * KK + k;
            int i0 = i0_s[idx];
            int i1 = i1_s[idx];
            float a0 = w0_s[idx];
            float a1 = w1_s[idx];
            float v0 = __bfloat162float(xab[i0 * CC]);
            float v1 = __bfloat162float(xab[i1 * CC]);
            acc = fmaf(a0, v0, fmaf(a1, v1, acc));
        }
        out_s[c][ll] = acc;
    }
    __syncthreads();

    // coalesced output write: out[n, g*32+r, l0+col]
    int col = t & (TILE_L - 1);
    int r0  = t >> 7;  // 0..1
    float* op = out + ((size_t)n * CC + (size_t)g * GCC) * LL + l0;
    for (int r = r0; r < GCC; r += 2) {
        op[(size_t)r * LL + col] = out_s[r][col];
    }
}

extern "C" void kernel_launch(void* const* d_in, const int* in_sizes, int n_in,
                              void* d_out, int out_size, void* d_ws, size_t ws_size,
                              hipStream_t stream) {
    const float* x    = (const float*)d_in[0];
    const float* ln_w = (const float*)d_in[1];
    const float* ln_b = (const float*)d_in[2];
    const float* om_w = (const float*)d_in[3];
    const float* om_b = (const float*)d_in[4];
    float* out = (float*)d_out;

    // ws layout
    float* wT = (float*)d_ws;                                   // 49152 B
    __hip_bfloat16* xa = (__hip_bfloat16*)((char*)d_ws + 49152); // 32 MB
    float* om = (float*)((char*)d_ws + 49152 + (size_t)NN * LL * CC * 2); // 12 MB

    k_transpose_w<<<(OMD * CC + 255) / 256, 256, 0, stream>>>(om_w, wT);

    k_ln_gelu_om<<<(NN * LL) / 256, 256, 0, stream>>>(x, ln_w, ln_b, wT, om_b, xa, om);

    dim3 grid2(LL / TILE_L, GG, NN);
    k_dcn<<<grid2, 256, 0, stream>>>(xa, om, out);
}

// Round 5
// 131.906 us; speedup vs baseline: 2.2814x; 2.2814x over previous
//
#include <hip/hip_runtime.h>
#include <hip/hip_bf16.h>
#include <math.h>

#define NN 8
#define CC 256
#define LL 8192
#define KK 3
#define GG 8
#define GCC 32
#define OMD 48  // 2*G*K
#define TILE_L 128
#define TL 32   // k1a positions per block

__device__ inline ushort f2bf(float f) {
    uint u = __float_as_uint(f);
    u += 0x7fffu + ((u >> 16) & 1u);   // RNE
    return (ushort)(u >> 16);
}
__device__ inline float bf2f(ushort s) {
    return __uint_as_float(((uint)s) << 16);
}

// ---------------- kernel 0: transpose om_w [48][256] -> wT [256][48] ----------
__global__ void k_transpose_w(const float* __restrict__ w, float* __restrict__ wT) {
    int idx = blockIdx.x * 256 + threadIdx.x;
    if (idx < OMD * CC) {
        int o = idx / CC, c = idx % CC;
        wT[c * OMD + o] = w[idx];
    }
}

// ---------------- kernel 1a: LN + GELU -> xa bf16 [N,L,C] ---------------------
// block = 256 thr = 32 positions x 8 channel-chunks. LDS-staged x tile.
// LDS layout: xs[c*33 + (p ^ ((c>>5)<<2))]  (stride 33 + XOR kills the
// 8-way sub-chunk bank conflict; residual 2-way aliasing is free).
__global__ __launch_bounds__(256) void k_ln_gelu(
    const float* __restrict__ x,
    const float* __restrict__ ln_w, const float* __restrict__ ln_b,
    __hip_bfloat16* __restrict__ xa)
{
    __shared__ float xs[CC * 33];   // 33792 B
    int n  = blockIdx.y;
    int l0 = blockIdx.x * TL;
    int t  = threadIdx.x;

    // stage x[n, 0:256, l0:l0+32] : 2048 float4 loads, 8 per thread
    const float* xbase = x + (size_t)n * CC * LL + l0;
    #pragma unroll
    for (int it = 0; it < 8; ++it) {
        int idx = it * 256 + t;        // float4 index 0..2047
        int c   = idx >> 3;            // channel
        int l4  = idx & 7;             // quad within 32-pos row
        float4 v = *reinterpret_cast<const float4*>(xbase + (size_t)c * LL + l4 * 4);
        int sw = (c >> 5) << 2;
        int b  = c * 33;
        xs[b + ((4 * l4 + 0) ^ sw)] = v.x;
        xs[b + ((4 * l4 + 1) ^ sw)] = v.y;
        xs[b + ((4 * l4 + 2) ^ sw)] = v.z;
        xs[b + ((4 * l4 + 3) ^ sw)] = v.w;
    }
    __syncthreads();

    int p   = t >> 3;        // position 0..31
    int sub = t & 7;         // channel chunk 0..7 (lanes 8p..8p+7 same position)
    int cb  = sub * 32;
    int sw  = sub << 2;      // == (c>>5)<<2 for c in [cb, cb+32)
    int pp  = p ^ sw;

    float r[32];
    #pragma unroll
    for (int j = 0; j < 32; ++j) r[j] = xs[(cb + j) * 33 + pp];

    float sum = 0.f, sq = 0.f;
    #pragma unroll
    for (int j = 0; j < 32; ++j) { sum += r[j]; sq = fmaf(r[j], r[j], sq); }
    #pragma unroll
    for (int m = 1; m <= 4; m <<= 1) {
        sum += __shfl_xor(sum, m);
        sq  += __shfl_xor(sq, m);
    }
    float mean = sum * (1.f / 256.f);
    float rstd = rsqrtf(sq * (1.f / 256.f) - mean * mean + 1e-6f);

    ushort pk[32];
    #pragma unroll
    for (int q = 0; q < 8; ++q) {
        float4 lw = *reinterpret_cast<const float4*>(ln_w + cb + 4 * q);
        float4 lb = *reinterpret_cast<const float4*>(ln_b + cb + 4 * q);
        float lww[4] = {lw.x, lw.y, lw.z, lw.w};
        float lbb[4] = {lb.x, lb.y, lb.z, lb.w};
        #pragma unroll
        for (int i = 0; i < 4; ++i) {
            int j = 4 * q + i;
            float xn = (r[j] - mean) * rstd * lww[i] + lbb[i];
            float g  = xn * 0.5f * (1.f + erff(xn * 0.70710678118654752440f));
            pk[j] = f2bf(g);
        }
    }

    // 64 B contiguous store: xa[n, l0+p, cb..cb+31]
    uint4* dst = reinterpret_cast<uint4*>(xa + ((size_t)n * LL + l0 + p) * CC + cb);
    #pragma unroll
    for (int q = 0; q < 4; ++q) {
        uint4 w4;
        w4.x = (uint)pk[8*q+0] | ((uint)pk[8*q+1] << 16);
        w4.y = (uint)pk[8*q+2] | ((uint)pk[8*q+3] << 16);
        w4.z = (uint)pk[8*q+4] | ((uint)pk[8*q+5] << 16);
        w4.w = (uint)pk[8*q+6] | ((uint)pk[8*q+7] << 16);
        dst[q] = w4;
    }
}

// ---------------- kernel 1b: om = xa @ wT + om_b ------------------------------
// block = 256 thr = 128 positions x 2 channel-halves. wT rows indexed by
// (sgpr cbase + loop counters) -> scalar s_load broadcasts, FMA-only VALU.
__global__ __launch_bounds__(256) void k_om(
    const __hip_bfloat16* __restrict__ xa, const float* __restrict__ wT,
    const float* __restrict__ om_b, float* __restrict__ om)
{
    __shared__ float red[128][OMD + 1];
    int t    = threadIdx.x;
    int pl   = t & 127;
    int half = t >> 7;                      // wave-uniform (waves 0,1 vs 2,3)
    int pos  = blockIdx.x * 128 + pl;
    int cbase = __builtin_amdgcn_readfirstlane(half * 128);

    float acc[OMD];
    #pragma unroll
    for (int o = 0; o < OMD; ++o) acc[o] = 0.f;

    const __hip_bfloat16* xrow = xa + (size_t)pos * CC + cbase;
    for (int j8 = 0; j8 < 16; ++j8) {       // 128 channels in octs of 8
        uint4 raw = *reinterpret_cast<const uint4*>(xrow + j8 * 8);
        uint rw[4] = {raw.x, raw.y, raw.z, raw.w};
        float g[8];
        #pragma unroll
        for (int d = 0; d < 4; ++d) {
            g[2*d]   = __uint_as_float(rw[d] << 16);
            g[2*d+1] = __uint_as_float(rw[d] & 0xffff0000u);
        }
        #pragma unroll
        for (int jj = 0; jj < 8; ++jj) {
            const float* wr = wT + (cbase + j8 * 8 + jj) * OMD;  // uniform addr
            #pragma unroll
            for (int o = 0; o < OMD; ++o) acc[o] = fmaf(g[jj], wr[o], acc[o]);
        }
    }

    if (half == 1) {
        #pragma unroll
        for (int o = 0; o < OMD; ++o) red[pl][o] = acc[o];
    }
    __syncthreads();
    if (half == 0) {
        #pragma unroll
        for (int o = 0; o < OMD; ++o) acc[o] += red[pl][o] + om_b[o];
        float* dst = om + (size_t)pos * OMD;
        #pragma unroll
        for (int o = 0; o < OMD; o += 4) {
            *reinterpret_cast<float4*>(dst + o) =
                make_float4(acc[o], acc[o+1], acc[o+2], acc[o+3]);
        }
    }
}

// ---------------- kernel 2: deformable gather + mask aggregation --------------
__global__ __launch_bounds__(256) void k_dcn(
    const __hip_bfloat16* __restrict__ xa, const float* __restrict__ om,
    float* __restrict__ out)
{
    int lt = blockIdx.x, g = blockIdx.y, n = blockIdx.z;
    int l0 = lt * TILE_L;

    __shared__ int   i0_s[TILE_L * KK];
    __shared__ int   i1_s[TILE_L * KK];
    __shared__ float w0_s[TILE_L * KK];
    __shared__ float w1_s[TILE_L * KK];
    __shared__ float out_s[GCC][TILE_L + 1];

    int t = threadIdx.x;

    for (int idx = t; idx < TILE_L * KK; idx += 256) {
        int ll = idx / KK, k = idx - KK * (idx / KK);
        int l = l0 + ll;
        const float* omp = om + ((size_t)n * LL + l) * OMD;
        float off  = omp[g * KK + k];
        float mask = omp[GG * KK + g * KK + k];
        float p  = (float)(l - 1 + k) + off;
        float p0 = floorf(p);
        float w1 = p - p0;
        float w0 = 1.f - w1;
        int i0 = (int)p0;
        int i1 = i0 + 1;
        float ws0 = (i0 >= 0 && i0 < LL) ? mask * w0 : 0.f;
        float ws1 = (i1 >= 0 && i1 < LL) ? mask * w1 : 0.f;
        i0_s[idx] = min(max(i0, 0), LL - 1);
        i1_s[idx] = min(max(i1, 0), LL - 1);
        w0_s[idx] = ws0;
        w1_s[idx] = ws1;
    }
    __syncthreads();

    int c  = t & 31;
    int lq = t >> 5;
    const __hip_bfloat16* xab = xa + (size_t)n * LL * CC + g * GCC + c;

    for (int it = 0; it < TILE_L / 8; ++it) {
        int ll = it * 8 + lq;
        float acc = 0.f;
        #pragma unroll
        for (int k = 0; k < KK; ++k) {
            int idx = ll * KK + k;
            float v0 = __bfloat162float(xab[i0_s[idx] * CC]);
            float v1 = __bfloat162float(xab[i1_s[idx] * CC]);
            acc = fmaf(w0_s[idx], v0, fmaf(w1_s[idx], v1, acc));
        }
        out_s[c][ll] = acc;
    }
    __syncthreads();

    int col = t & (TILE_L - 1);
    int r0  = t >> 7;
    float* op = out + ((size_t)n * CC + (size_t)g * GCC) * LL + l0;
    for (int r = r0; r < GCC; r += 2) {
        op[(size_t)r * LL + col] = out_s[r][col];
    }
}

extern "C" void kernel_launch(void* const* d_in, const int* in_sizes, int n_in,
                              void* d_out, int out_size, void* d_ws, size_t ws_size,
                              hipStream_t stream) {
    const float* x    = (const float*)d_in[0];
    const float* ln_w = (const float*)d_in[1];
    const float* ln_b = (const float*)d_in[2];
    const float* om_w = (const float*)d_in[3];
    const float* om_b = (const float*)d_in[4];
    float* out = (float*)d_out;

    float* wT = (float*)d_ws;                                    // 49152 B
    __hip_bfloat16* xa = (__hip_bfloat16*)((char*)d_ws + 49152); // 32 MB
    float* om = (float*)((char*)d_ws + 49152 + (size_t)NN * LL * CC * 2); // 12 MB

    k_transpose_w<<<(OMD * CC + 255) / 256, 256, 0, stream>>>(om_w, wT);

    dim3 g1a(LL / TL, NN);
    k_ln_gelu<<<g1a, 256, 0, stream>>>(x, ln_w, ln_b, xa);

    k_om<<<(NN * LL) / 128, 256, 0, stream>>>(xa, wT, om_b, om);

    dim3 grid2(LL / TILE_L, GG, NN);
    k_dcn<<<grid2, 256, 0, stream>>>(xa, om, out);
}

// Round 6
// 124.859 us; speedup vs baseline: 2.4102x; 1.0564x over previous
//
#include <hip/hip_runtime.h>
#include <hip/hip_bf16.h>
#include <math.h>

#define NN 8
#define CC 256
#define LL 8192
#define KK 3
#define GG 8
#define GCC 32
#define OMD 48  // 2*G*K
#define TILE_L 128
#define TL 32   // k1a positions per block

__device__ inline ushort f2bf(float f) {
    uint u = __float_as_uint(f);
    u += 0x7fffu + ((u >> 16) & 1u);   // RNE
    return (ushort)(u >> 16);
}

// ---------------- kernel 0: transpose om_w [48][256] -> wT [256][48] ----------
__global__ void k_transpose_w(const float* __restrict__ w, float* __restrict__ wT) {
    int idx = blockIdx.x * 256 + threadIdx.x;
    if (idx < OMD * CC) {
        int o = idx / CC, c = idx % CC;
        wT[c * OMD + o] = w[idx];
    }
}

// ---------------- kernel 1a: LN + GELU -> xa bf16 [N,L,C] ---------------------
// block = 256 thr = 32 positions x 8 channel-chunks. x tile staged through a
// 128-channel x 32-pos LDS buffer (16.9 KB) TWICE (half 0/1), parked in regs.
// Swizzle: xs[cl*33 + (l ^ ((cl>>4)<<2))] -> <=2-way bank aliasing both sides.
__global__ __launch_bounds__(256, 6) void k_ln_gelu(
    const float* __restrict__ x,
    const float* __restrict__ ln_w, const float* __restrict__ ln_b,
    __hip_bfloat16* __restrict__ xa)
{
    __shared__ float xs[128 * 33];   // 16896 B
    int n  = blockIdx.y;
    int l0 = blockIdx.x * TL;
    int t  = threadIdx.x;
    int p   = t >> 3;        // position 0..31
    int sub = t & 7;         // channel chunk 0..7
    int pp  = p ^ (sub << 2);

    const float* xbase = x + (size_t)n * CC * LL + l0;
    float r[32];

    #pragma unroll
    for (int half = 0; half < 2; ++half) {
        // issue all 4 tile loads first (independent, stay in flight)
        float4 v[4];
        #pragma unroll
        for (int it = 0; it < 4; ++it) {
            int idx = it * 256 + t;          // 0..1023
            int cl  = idx >> 3;              // local channel 0..127
            int l4  = idx & 7;               // quad within 32 positions
            v[it] = *reinterpret_cast<const float4*>(
                xbase + (size_t)(half * 128 + cl) * LL + l4 * 4);
        }
        if (half) __syncthreads();           // half-0 reads done before overwrite
        #pragma unroll
        for (int it = 0; it < 4; ++it) {
            int idx = it * 256 + t;
            int cl  = idx >> 3;
            int l4  = idx & 7;
            int sw  = (cl >> 4) << 2;
            int b   = cl * 33;
            xs[b + ((4 * l4 + 0) ^ sw)] = v[it].x;
            xs[b + ((4 * l4 + 1) ^ sw)] = v[it].y;
            xs[b + ((4 * l4 + 2) ^ sw)] = v[it].z;
            xs[b + ((4 * l4 + 3) ^ sw)] = v[it].w;
        }
        __syncthreads();
        // park this thread's 16 channels (c_local = sub*16 + j) in regs
        #pragma unroll
        for (int j = 0; j < 16; ++j)
            r[half * 16 + j] = xs[(sub * 16 + j) * 33 + pp];
    }

    // stats over 256 channels: 32 in-reg + reduce across 8 sub-lanes
    float sum = 0.f, sq = 0.f;
    #pragma unroll
    for (int j = 0; j < 32; ++j) { sum += r[j]; sq = fmaf(r[j], r[j], sq); }
    #pragma unroll
    for (int m = 1; m <= 4; m <<= 1) {
        sum += __shfl_xor(sum, m);
        sq  += __shfl_xor(sq, m);
    }
    float mean = sum * (1.f / 256.f);
    float rstd = rsqrtf(sq * (1.f / 256.f) - mean * mean + 1e-6f);

    // normalize + gelu + bf16 store; channels: half*128 + sub*16 + j
    __hip_bfloat16* xarow = xa + ((size_t)n * LL + l0 + p) * CC;
    #pragma unroll
    for (int half = 0; half < 2; ++half) {
        int cb = half * 128 + sub * 16;
        ushort pk[16];
        #pragma unroll
        for (int q = 0; q < 4; ++q) {
            float4 lw = *reinterpret_cast<const float4*>(ln_w + cb + 4 * q);
            float4 lb = *reinterpret_cast<const float4*>(ln_b + cb + 4 * q);
            float lww[4] = {lw.x, lw.y, lw.z, lw.w};
            float lbb[4] = {lb.x, lb.y, lb.z, lb.w};
            #pragma unroll
            for (int i = 0; i < 4; ++i) {
                int j = 4 * q + i;
                float xn = (r[half * 16 + j] - mean) * rstd * lww[i] + lbb[i];
                float g  = xn * 0.5f * (1.f + erff(xn * 0.70710678118654752440f));
                pk[j] = f2bf(g);
            }
        }
        uint4* dst = reinterpret_cast<uint4*>(xarow + cb);
        #pragma unroll
        for (int q = 0; q < 2; ++q) {
            uint4 w4;
            w4.x = (uint)pk[8*q+0] | ((uint)pk[8*q+1] << 16);
            w4.y = (uint)pk[8*q+2] | ((uint)pk[8*q+3] << 16);
            w4.z = (uint)pk[8*q+4] | ((uint)pk[8*q+5] << 16);
            w4.w = (uint)pk[8*q+6] | ((uint)pk[8*q+7] << 16);
            dst[q] = w4;
        }
    }
}

// ---------------- kernel 1b: om = xa @ wT + om_b ------------------------------
__global__ __launch_bounds__(256) void k_om(
    const __hip_bfloat16* __restrict__ xa, const float* __restrict__ wT,
    const float* __restrict__ om_b, float* __restrict__ om)
{
    __shared__ float red[128][OMD + 1];
    int t    = threadIdx.x;
    int pl   = t & 127;
    int half = t >> 7;                      // wave-uniform (waves 0,1 vs 2,3)
    int pos  = blockIdx.x * 128 + pl;
    int cbase = __builtin_amdgcn_readfirstlane(half * 128);

    float acc[OMD];
    #pragma unroll
    for (int o = 0; o < OMD; ++o) acc[o] = 0.f;

    const __hip_bfloat16* xrow = xa + (size_t)pos * CC + cbase;
    for (int j8 = 0; j8 < 16; ++j8) {       // 128 channels in octs of 8
        uint4 raw = *reinterpret_cast<const uint4*>(xrow + j8 * 8);
        uint rw[4] = {raw.x, raw.y, raw.z, raw.w};
        float g[8];
        #pragma unroll
        for (int d = 0; d < 4; ++d) {
            g[2*d]   = __uint_as_float(rw[d] << 16);
            g[2*d+1] = __uint_as_float(rw[d] & 0xffff0000u);
        }
        #pragma unroll
        for (int jj = 0; jj < 8; ++jj) {
            const float* wr = wT + (cbase + j8 * 8 + jj) * OMD;  // uniform addr
            #pragma unroll
            for (int o = 0; o < OMD; ++o) acc[o] = fmaf(g[jj], wr[o], acc[o]);
        }
    }

    if (half == 1) {
        #pragma unroll
        for (int o = 0; o < OMD; ++o) red[pl][o] = acc[o];
    }
    __syncthreads();
    if (half == 0) {
        #pragma unroll
        for (int o = 0; o < OMD; ++o) acc[o] += red[pl][o] + om_b[o];
        float* dst = om + (size_t)pos * OMD;
        #pragma unroll
        for (int o = 0; o < OMD; o += 4) {
            *reinterpret_cast<float4*>(dst + o) =
                make_float4(acc[o], acc[o+1], acc[o+2], acc[o+3]);
        }
    }
}

// ---------------- kernel 2: deformable gather + mask aggregation --------------
__global__ __launch_bounds__(256) void k_dcn(
    const __hip_bfloat16* __restrict__ xa, const float* __restrict__ om,
    float* __restrict__ out)
{
    int lt = blockIdx.x, g = blockIdx.y, n = blockIdx.z;
    int l0 = lt * TILE_L;

    __shared__ int   i0_s[TILE_L * KK];
    __shared__ int   i1_s[TILE_L * KK];
    __shared__ float w0_s[TILE_L * KK];
    __shared__ float w1_s[TILE_L * KK];
    __shared__ float out_s[GCC][TILE_L + 1];

    int t = threadIdx.x;

    for (int idx = t; idx < TILE_L * KK; idx += 256) {
        int ll = idx / KK, k = idx - KK * (idx / KK);
        int l = l0 + ll;
        const float* omp = om + ((size_t)n * LL + l) * OMD;
        float off  = omp[g * KK + k];
        float mask = omp[GG * KK + g * KK + k];
        float p  = (float)(l - 1 + k) + off;
        float p0 = floorf(p);
        float w1 = p - p0;
        float w0 = 1.f - w1;
        int i0 = (int)p0;
        int i1 = i0 + 1;
        float ws0 = (i0 >= 0 && i0 < LL) ? mask * w0 : 0.f;
        float ws1 = (i1 >= 0 && i1 < LL) ? mask * w1 : 0.f;
        i0_s[idx] = min(max(i0, 0), LL - 1);
        i1_s[idx] = min(max(i1, 0), LL - 1);
        w0_s[idx] = ws0;
        w1_s[idx] = ws1;
    }
    __syncthreads();

    int c  = t & 31;
    int lq = t >> 5;
    const __hip_bfloat16* xab = xa + (size_t)n * LL * CC + g * GCC + c;

    for (int it = 0; it < TILE_L / 8; ++it) {
        int ll = it * 8 + lq;
        float acc = 0.f;
        #pragma unroll
        for (int k = 0; k < KK; ++k) {
            int idx = ll * KK + k;
            float v0 = __bfloat162float(xab[i0_s[idx] * CC]);
            float v1 = __bfloat162float(xab[i1_s[idx] * CC]);
            acc = fmaf(w0_s[idx], v0, fmaf(w1_s[idx], v1, acc));
        }
        out_s[c][ll] = acc;
    }
    __syncthreads();

    int col = t & (TILE_L - 1);
    int r0  = t >> 7;
    float* op = out + ((size_t)n * CC + (size_t)g * GCC) * LL + l0;
    for (int r = r0; r < GCC; r += 2) {
        op[(size_t)r * LL + col] = out_s[r][col];
    }
}

extern "C" void kernel_launch(void* const* d_in, const int* in_sizes, int n_in,
                              void* d_out, int out_size, void* d_ws, size_t ws_size,
                              hipStream_t stream) {
    const float* x    = (const float*)d_in[0];
    const float* ln_w = (const float*)d_in[1];
    const float* ln_b = (const float*)d_in[2];
    const float* om_w = (const float*)d_in[3];
    const float* om_b = (const float*)d_in[4];
    float* out = (float*)d_out;

    float* wT = (float*)d_ws;                                    // 49152 B
    __hip_bfloat16* xa = (__hip_bfloat16*)((char*)d_ws + 49152); // 32 MB
    float* om = (float*)((char*)d_ws + 49152 + (size_t)NN * LL * CC * 2); // 12 MB

    k_transpose_w<<<(OMD * CC + 255) / 256, 256, 0, stream>>>(om_w, wT);

    dim3 g1a(LL / TL, NN);
    k_ln_gelu<<<g1a, 256, 0, stream>>>(x, ln_w, ln_b, xa);

    k_om<<<(NN * LL) / 128, 256, 0, stream>>>(xa, wT, om_b, om);

    dim3 grid2(LL / TILE_L, GG, NN);
    k_dcn<<<grid2, 256, 0, stream>>>(xa, om, out);
}

// Round 7
// 92.935 us; speedup vs baseline: 3.2381x; 1.3435x over previous
//
#include <hip/hip_runtime.h>
#include <hip/hip_bf16.h>
#include <math.h>

#define NN 8
#define CC 256
#define LL 8192
#define KK 3
#define GG 8
#define GCC 32
#define OMD 48  // 2*G*K
#define TILE_L 128
#define TL 32   // k1a positions per block

__device__ inline ushort f2bf(float f) {
    uint u = __float_as_uint(f);
    u += 0x7fffu + ((u >> 16) & 1u);   // RNE
    return (ushort)(u >> 16);
}

// branch-free GELU (tanh form) via hardware exp: max |err vs exact| ~3e-3
__device__ inline float gelu_fast(float xn) {
    float u = xn * xn;
    float z = xn * (-1.5957691216f - 0.0713548162726f * u);  // -2*0.79788456*(xn+0.044715 xn^3)
    return __fdividef(xn, 1.f + __expf(z));
}

// ---------------- kernel 0: transpose om_w [48][256] -> wT [256][48] ----------
__global__ void k_transpose_w(const float* __restrict__ w, float* __restrict__ wT) {
    int idx = blockIdx.x * 256 + threadIdx.x;
    if (idx < OMD * CC) {
        int o = idx / CC, c = idx % CC;
        wT[c * OMD + o] = w[idx];
    }
}

// ---------------- kernel 1a: LN + GELU -> xa bf16 [N,L,C] ---------------------
// block = 256 thr = 32 positions x 8 channel-chunks. x tile staged through a
// 128-channel x 32-pos LDS buffer (16.9 KB) TWICE (half 0/1), parked in regs.
// Swizzle: xs[cl*33 + (l ^ ((cl>>4)<<2))] -> <=2-way bank aliasing both sides.
__global__ __launch_bounds__(256, 6) void k_ln_gelu(
    const float* __restrict__ x,
    const float* __restrict__ ln_w, const float* __restrict__ ln_b,
    __hip_bfloat16* __restrict__ xa)
{
    __shared__ float xs[128 * 33];   // 16896 B
    int n  = blockIdx.y;
    int l0 = blockIdx.x * TL;
    int t  = threadIdx.x;
    int p   = t >> 3;        // position 0..31
    int sub = t & 7;         // channel chunk 0..7
    int pp  = p ^ (sub << 2);

    const float* xbase = x + (size_t)n * CC * LL + l0;
    float r[32];

    #pragma unroll
    for (int half = 0; half < 2; ++half) {
        // issue all 4 tile loads first (independent, stay in flight)
        float4 v[4];
        #pragma unroll
        for (int it = 0; it < 4; ++it) {
            int idx = it * 256 + t;          // 0..1023
            int cl  = idx >> 3;              // local channel 0..127
            int l4  = idx & 7;               // quad within 32 positions
            v[it] = *reinterpret_cast<const float4*>(
                xbase + (size_t)(half * 128 + cl) * LL + l4 * 4);
        }
        if (half) __syncthreads();           // half-0 reads done before overwrite
        #pragma unroll
        for (int it = 0; it < 4; ++it) {
            int idx = it * 256 + t;
            int cl  = idx >> 3;
            int l4  = idx & 7;
            int sw  = (cl >> 4) << 2;
            int b   = cl * 33;
            xs[b + ((4 * l4 + 0) ^ sw)] = v[it].x;
            xs[b + ((4 * l4 + 1) ^ sw)] = v[it].y;
            xs[b + ((4 * l4 + 2) ^ sw)] = v[it].z;
            xs[b + ((4 * l4 + 3) ^ sw)] = v[it].w;
        }
        __syncthreads();
        // park this thread's 16 channels (c_local = sub*16 + j) in regs
        #pragma unroll
        for (int j = 0; j < 16; ++j)
            r[half * 16 + j] = xs[(sub * 16 + j) * 33 + pp];
    }

    // stats over 256 channels: 32 in-reg + reduce across 8 sub-lanes
    float sum = 0.f, sq = 0.f;
    #pragma unroll
    for (int j = 0; j < 32; ++j) { sum += r[j]; sq = fmaf(r[j], r[j], sq); }
    #pragma unroll
    for (int m = 1; m <= 4; m <<= 1) {
        sum += __shfl_xor(sum, m);
        sq  += __shfl_xor(sq, m);
    }
    float mean = sum * (1.f / 256.f);
    float rstd = rsqrtf(sq * (1.f / 256.f) - mean * mean + 1e-6f);

    // normalize + gelu + bf16 store; channels: half*128 + sub*16 + j
    __hip_bfloat16* xarow = xa + ((size_t)n * LL + l0 + p) * CC;
    #pragma unroll
    for (int half = 0; half < 2; ++half) {
        int cb = half * 128 + sub * 16;
        ushort pk[16];
        #pragma unroll
        for (int q = 0; q < 4; ++q) {
            float4 lw = *reinterpret_cast<const float4*>(ln_w + cb + 4 * q);
            float4 lb = *reinterpret_cast<const float4*>(ln_b + cb + 4 * q);
            float lww[4] = {lw.x, lw.y, lw.z, lw.w};
            float lbb[4] = {lb.x, lb.y, lb.z, lb.w};
            #pragma unroll
            for (int i = 0; i < 4; ++i) {
                int j = 4 * q + i;
                float xn = (r[half * 16 + j] - mean) * rstd * lww[i] + lbb[i];
                pk[j] = f2bf(gelu_fast(xn));
            }
        }
        uint4* dst = reinterpret_cast<uint4*>(xarow + cb);
        #pragma unroll
        for (int q = 0; q < 2; ++q) {
            uint4 w4;
            w4.x = (uint)pk[8*q+0] | ((uint)pk[8*q+1] << 16);
            w4.y = (uint)pk[8*q+2] | ((uint)pk[8*q+3] << 16);
            w4.z = (uint)pk[8*q+4] | ((uint)pk[8*q+5] << 16);
            w4.w = (uint)pk[8*q+6] | ((uint)pk[8*q+7] << 16);
            dst[q] = w4;
        }
    }
}

// ---------------- kernel 1b: om = xa @ wT + om_b ------------------------------
__global__ __launch_bounds__(256) void k_om(
    const __hip_bfloat16* __restrict__ xa, const float* __restrict__ wT,
    const float* __restrict__ om_b, float* __restrict__ om)
{
    __shared__ float red[128][OMD + 1];
    int t    = threadIdx.x;
    int pl   = t & 127;
    int half = t >> 7;                      // wave-uniform (waves 0,1 vs 2,3)
    int pos  = blockIdx.x * 128 + pl;
    int cbase = __builtin_amdgcn_readfirstlane(half * 128);

    float acc[OMD];
    #pragma unroll
    for (int o = 0; o < OMD; ++o) acc[o] = 0.f;

    const __hip_bfloat16* xrow = xa + (size_t)pos * CC + cbase;
    for (int j8 = 0; j8 < 16; ++j8) {       // 128 channels in octs of 8
        uint4 raw = *reinterpret_cast<const uint4*>(xrow + j8 * 8);
        uint rw[4] = {raw.x, raw.y, raw.z, raw.w};
        float g[8];
        #pragma unroll
        for (int d = 0; d < 4; ++d) {
            g[2*d]   = __uint_as_float(rw[d] << 16);
            g[2*d+1] = __uint_as_float(rw[d] & 0xffff0000u);
        }
        #pragma unroll
        for (int jj = 0; jj < 8; ++jj) {
            const float* wr = wT + (cbase + j8 * 8 + jj) * OMD;  // uniform addr
            #pragma unroll
            for (int o = 0; o < OMD; ++o) acc[o] = fmaf(g[jj], wr[o], acc[o]);
        }
    }

    if (half == 1) {
        #pragma unroll
        for (int o = 0; o < OMD; ++o) red[pl][o] = acc[o];
    }
    __syncthreads();
    if (half == 0) {
        #pragma unroll
        for (int o = 0; o < OMD; ++o) acc[o] += red[pl][o] + om_b[o];
        float* dst = om + (size_t)pos * OMD;
        #pragma unroll
        for (int o = 0; o < OMD; o += 4) {
            *reinterpret_cast<float4*>(dst + o) =
                make_float4(acc[o], acc[o+1], acc[o+2], acc[o+3]);
        }
    }
}

// ---------------- kernel 2: deformable gather + mask aggregation --------------
// thread owns 4 consecutive channels (uint2 = 8B gathers, 64B per 8-lane group)
__global__ __launch_bounds__(256) void k_dcn(
    const __hip_bfloat16* __restrict__ xa, const float* __restrict__ om,
    float* __restrict__ out)
{
    int lt = blockIdx.x, g = blockIdx.y, n = blockIdx.z;
    int l0 = lt * TILE_L;

    __shared__ int   i0_s[TILE_L * KK];
    __shared__ int   i1_s[TILE_L * KK];
    __shared__ float w0_s[TILE_L * KK];
    __shared__ float w1_s[TILE_L * KK];
    __shared__ float out_s[GCC][TILE_L + 1];

    int t = threadIdx.x;

    for (int idx = t; idx < TILE_L * KK; idx += 256) {
        int ll = idx / KK, k = idx - KK * (idx / KK);
        int l = l0 + ll;
        const float* omp = om + ((size_t)n * LL + l) * OMD;
        float off  = omp[g * KK + k];
        float mask = omp[GG * KK + g * KK + k];
        float p  = (float)(l - 1 + k) + off;
        float p0 = floorf(p);
        float w1 = p - p0;
        float w0 = 1.f - w1;
        int i0 = (int)p0;
        int i1 = i0 + 1;
        float ws0 = (i0 >= 0 && i0 < LL) ? mask * w0 : 0.f;
        float ws1 = (i1 >= 0 && i1 < LL) ? mask * w1 : 0.f;
        i0_s[idx] = min(max(i0, 0), LL - 1);
        i1_s[idx] = min(max(i1, 0), LL - 1);
        w0_s[idx] = ws0;
        w1_s[idx] = ws1;
    }
    __syncthreads();

    int cq = t & 7;        // channel quad: channels 4cq..4cq+3
    int ps = t >> 3;       // position slot 0..31
    const __hip_bfloat16* xab = xa + (size_t)n * LL * CC + g * GCC + cq * 4;

    #pragma unroll
    for (int it = 0; it < TILE_L / 32; ++it) {
        int ll = it * 32 + ps;
        float acc0 = 0.f, acc1 = 0.f, acc2 = 0.f, acc3 = 0.f;
        #pragma unroll
        for (int k = 0; k < KK; ++k) {
            int idx = ll * KK + k;
            int i0 = i0_s[idx];
            int i1 = i1_s[idx];
            float a0 = w0_s[idx];
            float a1 = w1_s[idx];
            uint2 r0 = *reinterpret_cast<const uint2*>(xab + (size_t)i0 * CC);
            uint2 r1 = *reinterpret_cast<const uint2*>(xab + (size_t)i1 * CC);
            float v00 = __uint_as_float(r0.x << 16);
            float v01 = __uint_as_float(r0.x & 0xffff0000u);
            float v02 = __uint_as_float(r0.y << 16);
            float v03 = __uint_as_float(r0.y & 0xffff0000u);
            float v10 = __uint_as_float(r1.x << 16);
            float v11 = __uint_as_float(r1.x & 0xffff0000u);
            float v12 = __uint_as_float(r1.y << 16);
            float v13 = __uint_as_float(r1.y & 0xffff0000u);
            acc0 = fmaf(a0, v00, fmaf(a1, v10, acc0));
            acc1 = fmaf(a0, v01, fmaf(a1, v11, acc1));
            acc2 = fmaf(a0, v02, fmaf(a1, v12, acc2));
            acc3 = fmaf(a0, v03, fmaf(a1, v13, acc3));
        }
        out_s[cq * 4 + 0][ll] = acc0;
        out_s[cq * 4 + 1][ll] = acc1;
        out_s[cq * 4 + 2][ll] = acc2;
        out_s[cq * 4 + 3][ll] = acc3;
    }
    __syncthreads();

    int col = t & (TILE_L - 1);
    int r0  = t >> 7;
    float* op = out + ((size_t)n * CC + (size_t)g * GCC) * LL + l0;
    for (int r = r0; r < GCC; r += 2) {
        op[(size_t)r * LL + col] = out_s[r][col];
    }
}

extern "C" void kernel_launch(void* const* d_in, const int* in_sizes, int n_in,
                              void* d_out, int out_size, void* d_ws, size_t ws_size,
                              hipStream_t stream) {
    const float* x    = (const float*)d_in[0];
    const float* ln_w = (const float*)d_in[1];
    const float* ln_b = (const float*)d_in[2];
    const float* om_w = (const float*)d_in[3];
    const float* om_b = (const float*)d_in[4];
    float* out = (float*)d_out;

    float* wT = (float*)d_ws;                                    // 49152 B
    __hip_bfloat16* xa = (__hip_bfloat16*)((char*)d_ws + 49152); // 32 MB
    float* om = (float*)((char*)d_ws + 49152 + (size_t)NN * LL * CC * 2); // 12 MB

    k_transpose_w<<<(OMD * CC + 255) / 256, 256, 0, stream>>>(om_w, wT);

    dim3 g1a(LL / TL, NN);
    k_ln_gelu<<<g1a, 256, 0, stream>>>(x, ln_w, ln_b, xa);

    k_om<<<(NN * LL) / 128, 256, 0, stream>>>(xa, wT, om_b, om);

    dim3 grid2(LL / TILE_L, GG, NN);
    k_dcn<<<grid2, 256, 0, stream>>>(xa, om, out);
}

// Round 8
// 64.238 us; speedup vs baseline: 4.6847x; 1.4467x over previous
//
#include <hip/hip_runtime.h>
#include <hip/hip_bf16.h>
#include <math.h>

#define NN 8
#define CC 256
#define LL 8192
#define KK 3
#define GG 8
#define GCC 32
#define OMD 48  // 2*G*K
#define TILE_L 128
#define TL 32   // k1a positions per block

typedef __attribute__((ext_vector_type(8))) short short8v;   // 8 bf16 (4 VGPR)
typedef __attribute__((ext_vector_type(4))) float floatx4;

__device__ inline ushort f2bf(float f) {
    uint u = __float_as_uint(f);
    u += 0x7fffu + ((u >> 16) & 1u);   // RNE
    return (ushort)(u >> 16);
}

// branch-free GELU (tanh form) via hardware exp: max |err vs exact| ~3e-3
__device__ inline float gelu_fast(float xn) {
    float u = xn * xn;
    float z = xn * (-1.5957691216f - 0.0713548162726f * u);
    return __fdividef(xn, 1.f + __expf(z));
}

// ---- kernel 0: pack om_w [48][256] into MFMA B-fragment order, bf16 ----------
// wB[((ks*3+nt)*64 + lane)*8 + j] = om_w[16*nt + (lane&15)][32*ks + 8*(lane>>4) + j]
__global__ void k_prep_w(const float* __restrict__ om_w, ushort* __restrict__ wB) {
    int idx = blockIdx.x * 256 + threadIdx.x;   // 12288 total
    if (idx < 8 * 3 * 64 * 8) {
        int j  = idx & 7;
        int l  = (idx >> 3) & 63;
        int nt = (idx >> 9) % 3;
        int ks = idx / 1536;
        int o  = 16 * nt + (l & 15);
        int c  = 32 * ks + 8 * (l >> 4) + j;
        wB[idx] = f2bf(om_w[o * CC + c]);
    }
}

// ---------------- kernel 1a: LN + GELU -> xa bf16 [N,L,C] ---------------------
__global__ __launch_bounds__(256, 6) void k_ln_gelu(
    const float* __restrict__ x,
    const float* __restrict__ ln_w, const float* __restrict__ ln_b,
    __hip_bfloat16* __restrict__ xa)
{
    __shared__ float xs[128 * 33];   // 16896 B
    int n  = blockIdx.y;
    int l0 = blockIdx.x * TL;
    int t  = threadIdx.x;
    int p   = t >> 3;        // position 0..31
    int sub = t & 7;         // channel chunk 0..7
    int pp  = p ^ (sub << 2);

    const float* xbase = x + (size_t)n * CC * LL + l0;
    float r[32];

    #pragma unroll
    for (int half = 0; half < 2; ++half) {
        float4 v[4];
        #pragma unroll
        for (int it = 0; it < 4; ++it) {
            int idx = it * 256 + t;
            int cl  = idx >> 3;
            int l4  = idx & 7;
            v[it] = *reinterpret_cast<const float4*>(
                xbase + (size_t)(half * 128 + cl) * LL + l4 * 4);
        }
        if (half) __syncthreads();
        #pragma unroll
        for (int it = 0; it < 4; ++it) {
            int idx = it * 256 + t;
            int cl  = idx >> 3;
            int l4  = idx & 7;
            int sw  = (cl >> 4) << 2;
            int b   = cl * 33;
            xs[b + ((4 * l4 + 0) ^ sw)] = v[it].x;
            xs[b + ((4 * l4 + 1) ^ sw)] = v[it].y;
            xs[b + ((4 * l4 + 2) ^ sw)] = v[it].z;
            xs[b + ((4 * l4 + 3) ^ sw)] = v[it].w;
        }
        __syncthreads();
        #pragma unroll
        for (int j = 0; j < 16; ++j)
            r[half * 16 + j] = xs[(sub * 16 + j) * 33 + pp];
    }

    float sum = 0.f, sq = 0.f;
    #pragma unroll
    for (int j = 0; j < 32; ++j) { sum += r[j]; sq = fmaf(r[j], r[j], sq); }
    #pragma unroll
    for (int m = 1; m <= 4; m <<= 1) {
        sum += __shfl_xor(sum, m);
        sq  += __shfl_xor(sq, m);
    }
    float mean = sum * (1.f / 256.f);
    float rstd = rsqrtf(sq * (1.f / 256.f) - mean * mean + 1e-6f);

    __hip_bfloat16* xarow = xa + ((size_t)n * LL + l0 + p) * CC;
    #pragma unroll
    for (int half = 0; half < 2; ++half) {
        int cb = half * 128 + sub * 16;
        ushort pk[16];
        #pragma unroll
        for (int q = 0; q < 4; ++q) {
            float4 lw = *reinterpret_cast<const float4*>(ln_w + cb + 4 * q);
            float4 lb = *reinterpret_cast<const float4*>(ln_b + cb + 4 * q);
            float lww[4] = {lw.x, lw.y, lw.z, lw.w};
            float lbb[4] = {lb.x, lb.y, lb.z, lb.w};
            #pragma unroll
            for (int i = 0; i < 4; ++i) {
                int j = 4 * q + i;
                float xn = (r[half * 16 + j] - mean) * rstd * lww[i] + lbb[i];
                pk[j] = f2bf(gelu_fast(xn));
            }
        }
        uint4* dst = reinterpret_cast<uint4*>(xarow + cb);
        #pragma unroll
        for (int q = 0; q < 2; ++q) {
            uint4 w4;
            w4.x = (uint)pk[8*q+0] | ((uint)pk[8*q+1] << 16);
            w4.y = (uint)pk[8*q+2] | ((uint)pk[8*q+3] << 16);
            w4.z = (uint)pk[8*q+4] | ((uint)pk[8*q+5] << 16);
            w4.w = (uint)pk[8*q+6] | ((uint)pk[8*q+7] << 16);
            dst[q] = w4;
        }
    }
}

// ---------------- kernel 1b: om = xa @ wB + om_b via MFMA ---------------------
// one wave per 16-position M-tile; K=256 in 8 steps of 32; N=48 as 3 n-tiles.
__global__ __launch_bounds__(256, 4) void k_om_mfma(
    const __hip_bfloat16* __restrict__ xa, const ushort* __restrict__ wB,
    const float* __restrict__ om_b, float* __restrict__ om)
{
    int t    = threadIdx.x;
    int lane = t & 63;
    int w    = blockIdx.x * 4 + (t >> 6);   // mtile id 0..4095
    int col  = lane & 15;                   // A-row / C-col
    int q    = lane >> 4;                   // k-subgroup / C row-quad
    size_t pos0 = (size_t)w * 16;

    const short8v* Abase = reinterpret_cast<const short8v*>(
        reinterpret_cast<const ushort*>(xa) + (pos0 + col) * CC + q * 8);
    const short8v* Bbase = reinterpret_cast<const short8v*>(wB) + lane;

    floatx4 acc[3] = {{0.f,0.f,0.f,0.f},{0.f,0.f,0.f,0.f},{0.f,0.f,0.f,0.f}};
    #pragma unroll
    for (int ks = 0; ks < 8; ++ks) {
        short8v a = Abase[ks * 4];          // +32 channels per step
        #pragma unroll
        for (int nt = 0; nt < 3; ++nt) {
            short8v b = Bbase[(ks * 3 + nt) * 64];
            acc[nt] = __builtin_amdgcn_mfma_f32_16x16x32_bf16(a, b, acc[nt], 0, 0, 0);
        }
    }
    #pragma unroll
    for (int nt = 0; nt < 3; ++nt) {
        float bias = om_b[nt * 16 + col];
        float* dst = om + (pos0 + q * 4) * OMD + nt * 16 + col;
        #pragma unroll
        for (int i = 0; i < 4; ++i)
            dst[(size_t)i * OMD] = acc[nt][i] + bias;
    }
}

// ---------------- kernel 2: deformable gather + mask aggregation --------------
__global__ __launch_bounds__(256) void k_dcn(
    const __hip_bfloat16* __restrict__ xa, const float* __restrict__ om,
    float* __restrict__ out)
{
    int lt = blockIdx.x, g = blockIdx.y, n = blockIdx.z;
    int l0 = lt * TILE_L;

    __shared__ int   i0_s[TILE_L * KK];
    __shared__ int   i1_s[TILE_L * KK];
    __shared__ float w0_s[TILE_L * KK];
    __shared__ float w1_s[TILE_L * KK];
    __shared__ float out_s[GCC][TILE_L + 1];

    int t = threadIdx.x;

    for (int idx = t; idx < TILE_L * KK; idx += 256) {
        int ll = idx / KK, k = idx - KK * (idx / KK);
        int l = l0 + ll;
        const float* omp = om + ((size_t)n * LL + l) * OMD;
        float off  = omp[g * KK + k];
        float mask = omp[GG * KK + g * KK + k];
        float p  = (float)(l - 1 + k) + off;
        float p0 = floorf(p);
        float w1 = p - p0;
        float w0 = 1.f - w1;
        int i0 = (int)p0;
        int i1 = i0 + 1;
        float ws0 = (i0 >= 0 && i0 < LL) ? mask * w0 : 0.f;
        float ws1 = (i1 >= 0 && i1 < LL) ? mask * w1 : 0.f;
        i0_s[idx] = min(max(i0, 0), LL - 1);
        i1_s[idx] = min(max(i1, 0), LL - 1);
        w0_s[idx] = ws0;
        w1_s[idx] = ws1;
    }
    __syncthreads();

    int cq = t & 7;        // channel quad: channels 4cq..4cq+3
    int ps = t >> 3;       // position slot 0..31
    const __hip_bfloat16* xab = xa + (size_t)n * LL * CC + g * GCC + cq * 4;

    #pragma unroll
    for (int it = 0; it < TILE_L / 32; ++it) {
        int ll = it * 32 + ps;
        float acc0 = 0.f, acc1 = 0.f, acc2 = 0.f, acc3 = 0.f;
        #pragma unroll
        for (int k = 0; k < KK; ++k) {
            int idx = ll * KK + k;
            int i0 = i0_s[idx];
            int i1 = i1_s[idx];
            float a0 = w0_s[idx];
            float a1 = w1_s[idx];
            uint2 r0 = *reinterpret_cast<const uint2*>(xab + (size_t)i0 * CC);
            uint2 r1 = *reinterpret_cast<const uint2*>(xab + (size_t)i1 * CC);
            float v00 = __uint_as_float(r0.x << 16);
            float v01 = __uint_as_float(r0.x & 0xffff0000u);
            float v02 = __uint_as_float(r0.y << 16);
            float v03 = __uint_as_float(r0.y & 0xffff0000u);
            float v10 = __uint_as_float(r1.x << 16);
            float v11 = __uint_as_float(r1.x & 0xffff0000u);
            float v12 = __uint_as_float(r1.y << 16);
            float v13 = __uint_as_float(r1.y & 0xffff0000u);
            acc0 = fmaf(a0, v00, fmaf(a1, v10, acc0));
            acc1 = fmaf(a0, v01, fmaf(a1, v11, acc1));
            acc2 = fmaf(a0, v02, fmaf(a1, v12, acc2));
            acc3 = fmaf(a0, v03, fmaf(a1, v13, acc3));
        }
        out_s[cq * 4 + 0][ll] = acc0;
        out_s[cq * 4 + 1][ll] = acc1;
        out_s[cq * 4 + 2][ll] = acc2;
        out_s[cq * 4 + 3][ll] = acc3;
    }
    __syncthreads();

    int col = t & (TILE_L - 1);
    int r0  = t >> 7;
    float* op = out + ((size_t)n * CC + (size_t)g * GCC) * LL + l0;
    for (int r = r0; r < GCC; r += 2) {
        op[(size_t)r * LL + col] = out_s[r][col];
    }
}

extern "C" void kernel_launch(void* const* d_in, const int* in_sizes, int n_in,
                              void* d_out, int out_size, void* d_ws, size_t ws_size,
                              hipStream_t stream) {
    const float* x    = (const float*)d_in[0];
    const float* ln_w = (const float*)d_in[1];
    const float* ln_b = (const float*)d_in[2];
    const float* om_w = (const float*)d_in[3];
    const float* om_b = (const float*)d_in[4];
    float* out = (float*)d_out;

    ushort* wB = (ushort*)d_ws;                                  // 24576 B
    __hip_bfloat16* xa = (__hip_bfloat16*)((char*)d_ws + 49152); // 32 MB
    float* om = (float*)((char*)d_ws + 49152 + (size_t)NN * LL * CC * 2); // 12 MB

    k_prep_w<<<48, 256, 0, stream>>>(om_w, wB);

    dim3 g1a(LL / TL, NN);
    k_ln_gelu<<<g1a, 256, 0, stream>>>(x, ln_w, ln_b, xa);

    k_om_mfma<<<1024, 256, 0, stream>>>(xa, wB, om_b, om);

    dim3 grid2(LL / TILE_L, GG, NN);
    k_dcn<<<grid2, 256, 0, stream>>>(xa, om, out);
}